// Round 6
// baseline (384.163 us; speedup 1.0000x reference)
//
#include <hip/hip_runtime.h>
#include <math.h>

// Problem constants (B=4, L=8192, SEG=2048, RATE=4, D=768)
#define SEGLEN 2048
#define SRATE 4
#define DIM 768
#define BATCH 4
#define LFULL 8192
#define LSP 2048                 // sparsified length per batch (4 segs * 512)
#define NROWS (BATCH * LSP)      // 8192 total sparsified rows
#define LN_EPS 1e-5f
#define ATT_SCALE 0.03608439182435161f   // 1/sqrt(768)

typedef __attribute__((ext_vector_type(8))) short s16x8;
typedef __attribute__((ext_vector_type(4))) float f32x4;

__device__ __forceinline__ ushort f2bf(float f) {
    unsigned u = __float_as_uint(f);
    u += 0x7fffu + ((u >> 16) & 1u);      // RNE
    return (ushort)(u >> 16);
}
__device__ __forceinline__ float bf2f(ushort h) {
    return __uint_as_float(((unsigned)h) << 16);
}

// async global->LDS, 16B per lane. LDS dest is wave-uniform base + lane*16.
__device__ __forceinline__ void ld_lds16(const ushort* g, ushort* l) {
    __builtin_amdgcn_global_load_lds(
        (const __attribute__((address_space(1))) void*)g,
        (__attribute__((address_space(3))) void*)l, 16, 0, 0);
}

// ---------------------------------------------------------------------------
// Gather sparsified rows + fp32->bf16; z==3 converts the three weight mats.
// ---------------------------------------------------------------------------
__global__ void pack4(const float* __restrict__ Q, const float* __restrict__ Ks,
                      const float* __restrict__ V, const float* __restrict__ Wq,
                      const float* __restrict__ Wk, const float* __restrict__ Wv,
                      ushort* __restrict__ X, ushort* __restrict__ W) {
    const int z = blockIdx.z;
    int idx = blockIdx.x * 256 + threadIdx.x;        // one per 4 elements
    if (z == 3) {
        if (idx < 3 * (DIM * DIM / 4)) {
            int ww = idx / (DIM * DIM / 4);
            int r = idx - ww * (DIM * DIM / 4);
            const float* src = ww == 0 ? Wq : ww == 1 ? Wk : Wv;
            float4 f = *(const float4*)(src + (long)r * 4);
            ushort4 o;
            o.x = f2bf(f.x); o.y = f2bf(f.y); o.z = f2bf(f.z); o.w = f2bf(f.w);
            *(ushort4*)(W + (long)ww * DIM * DIM + (long)r * 4) = o;
        }
        return;
    }
    const float* src = z == 0 ? Q : z == 1 ? Ks : V;
    ushort* dst = X + (long)z * (NROWS * DIM);
    int r  = idx / (DIM / 4);
    int dg = idx - r * (DIM / 4);
    int bb = r >> 11;            // /2048
    int s  = r & 2047;
    int seg = s >> 9;            // /512
    int j   = s & 511;
    long srow = (long)bb * LFULL + seg * SEGLEN + j * SRATE;
    float4 f = *(const float4*)(src + srow * DIM + dg * 4);
    ushort4 o;
    o.x = f2bf(f.x); o.y = f2bf(f.y); o.z = f2bf(f.z); o.w = f2bf(f.w);
    *(ushort4*)(dst + (long)r * DIM + dg * 4) = o;
}

// ---------------------------------------------------------------------------
// BT-GEMM: C[i][j] = sum_k A[i][k]*B[j][k], bf16 operands K-contiguous.
// 128x128 tile, BK=64, **512 thr = 8 waves (4M x 2N), wave tile 32x64,
// acc[2][4]** — this round's change: 2 blocks/CU x 8 waves = 16 waves/CU
// (~50% occupancy, 4 waves/SIMD) vs round 5's 8 waves/CU (19% measured).
// Same 64 KiB LDS, same ks-pure deep pipeline with counted vmcnt (per-wave
// ledger exactly halved: steady vmcnt(4), tail 2 -> 0), same st_16x32
// swizzle (0 conflicts measured), same m204 XCD remap.
// MODE 0: z<2 -> bf16 row-major to Cb+z*sC; z==2 -> transposed vT to Cb2 [proj]
// MODE 2: e=__expf(acc*scale); bf16 P row-major + atomicAdd row-sums     [QK]
// MODE 3: split-K: z=(batch,half); fp32 row-major to (half? Cf2 : Cf)   [PV]
// ---------------------------------------------------------------------------
template<int MODE, int NT>
__global__ __launch_bounds__(512, 4) void gemm_bt(
    const ushort* __restrict__ Ag, const ushort* __restrict__ Bg,
    ushort* __restrict__ Cb, ushort* __restrict__ Cb2,
    float* __restrict__ Cf, float* __restrict__ Cf2, float* __restrict__ lsum,
    int M, int N, int lda, int ldb, long sA, long sB, long sC,
    int ldc, float scale)
{
    __shared__ ushort lds[2][2][8192];   // [dbuf][A/B][16KB] = 64 KiB
    const int K = NT * 64;

    // --- XCD-chunked bijective remap (m204; grid sizes all divisible by 8)
    const int gx = gridDim.x, gy = gridDim.y;
    const int G = gx * gy * gridDim.z;
    const int f = blockIdx.x + gx * (blockIdx.y + gy * blockIdx.z);
    const int wg = (f & 7) * (G >> 3) + (f >> 3);
    const int bx = wg % gx;
    const int rest = wg / gx;
    const int by = rest % gy;
    const int z  = rest / gy;

    const int bz = (MODE == 3) ? (z >> 1) : z;
    const int hz = (MODE == 3) ? (z & 1) : 0;
    const ushort* Aop = Ag + (long)bz * sA + (long)hz * K;
    const ushort* Bop = Bg + (long)bz * sB + (long)hz * K;

    const int tid = threadIdx.x;
    const int w = tid >> 6, lane = tid & 63;
    const int wm = w >> 1, wn = w & 1;          // 4M x 2N wave grid
    const int quad = lane >> 4, lr = lane & 15;
    const int rowBase = by * 128;
    const int colBase = bx * 128;

    // per-lane ds_read byte offset within a 1024B (16x32) subtile, swizzled
    int ib = ((lane & 15) << 6) | ((lane >> 4) << 4);
    ib ^= ((ib >> 9) & 1) << 5;

    // staging: each thread owns ONE 16B chunk per 8KB half-tile (c = tid).
    // Linear LDS dest; global source inverse-swizzled (rule #21).
    long offA, offB;
    {
        int c = tid;
        int cc = c ^ (((c >> 5) & 1) << 1);      // byte-bit5 flip == chunk-bit1
        int s = cc >> 6;                          // rowgroup 0..7
        int row  = s * 16 + ((cc >> 2) & 15);
        int colE = (cc & 3) << 3;
        offA = (long)(rowBase + row) * lda + colE;
        offB = (long)(colBase + row) * ldb + colE;
    }

#define STA(buf, vv, h) ld_lds16(Aop + offA + (long)(vv) * 64 + (h) * 32, &lds[buf][0][(h) * 4096 + w * 512])
#define STB(buf, vv, h) ld_lds16(Bop + offB + (long)(vv) * 64 + (h) * 32, &lds[buf][1][(h) * 4096 + w * 512])

    // prologue: H0(0), H1(0), H0(1) -> 6 outstanding loads per wave
    STA(0, 0, 0); STB(0, 0, 0);
    STA(0, 0, 1); STB(0, 0, 1);
    STA(1, 1, 0); STB(1, 1, 0);

    f32x4 acc[2][4] = {};

    for (int v = 0; v < NT; ++v) {
        const int b = v & 1;
        const char* lA = (const char*)&lds[b][0][0];
        const char* lB = (const char*)&lds[b][1][0];

        // ---- phase ks=0: needs H0(v); issue H1(v+1)
        if (v < NT - 1) asm volatile("s_waitcnt vmcnt(4)" ::: "memory");
        else            asm volatile("s_waitcnt vmcnt(2)" ::: "memory");
        __builtin_amdgcn_s_barrier();
        if (v + 1 < NT) { STA(b ^ 1, v + 1, 1); STB(b ^ 1, v + 1, 1); }
        {
            s16x8 aq[2], bq[4];
#pragma unroll
            for (int i = 0; i < 2; ++i)
                aq[i] = *(const s16x8*)(lA + ((wm * 2 + i) << 10) + ib);
#pragma unroll
            for (int j = 0; j < 4; ++j)
                bq[j] = *(const s16x8*)(lB + ((wn * 4 + j) << 10) + ib);
            __builtin_amdgcn_s_setprio(1);
#pragma unroll
            for (int i = 0; i < 2; i++)
#pragma unroll
                for (int j = 0; j < 4; j++)
                    acc[i][j] = __builtin_amdgcn_mfma_f32_16x16x32_bf16(
                        aq[i], bq[j], acc[i][j], 0, 0, 0);
            __builtin_amdgcn_s_setprio(0);
        }

        // ---- phase ks=1: needs H1(v); issue H0(v+2)
        if (v < NT - 1) asm volatile("s_waitcnt vmcnt(4)" ::: "memory");
        else            asm volatile("s_waitcnt vmcnt(0)" ::: "memory");
        __builtin_amdgcn_s_barrier();
        if (v + 2 < NT) { STA(b, v + 2, 0); STB(b, v + 2, 0); }
        {
            s16x8 aq[2], bq[4];
#pragma unroll
            for (int i = 0; i < 2; ++i)
                aq[i] = *(const s16x8*)(lA + ((8 + wm * 2 + i) << 10) + ib);
#pragma unroll
            for (int j = 0; j < 4; ++j)
                bq[j] = *(const s16x8*)(lB + ((8 + wn * 4 + j) << 10) + ib);
            __builtin_amdgcn_s_setprio(1);
#pragma unroll
            for (int i = 0; i < 2; i++)
#pragma unroll
                for (int j = 0; j < 4; j++)
                    acc[i][j] = __builtin_amdgcn_mfma_f32_16x16x32_bf16(
                        aq[i], bq[j], acc[i][j], 0, 0, 0);
            __builtin_amdgcn_s_setprio(0);
        }
    }
#undef STA
#undef STB

    // Epilogue. D mapping: col = lane&15, row = quad*4+reg (guide §3).
    if (MODE == 0) {
        if (z < 2) {
            ushort* Cz = Cb + (long)z * sC;
#pragma unroll
            for (int i = 0; i < 2; i++) {
                int r0 = rowBase + wm * 32 + i * 16 + quad * 4;
#pragma unroll
                for (int j = 0; j < 4; j++) {
                    int c = colBase + wn * 64 + j * 16 + lr;
#pragma unroll
                    for (int reg = 0; reg < 4; reg++)
                        Cz[(long)(r0 + reg) * ldc + c] = f2bf(acc[i][j][reg]);
                }
            }
        } else {
            // v-projection: store transposed vT[b][col][row]
#pragma unroll
            for (int i = 0; i < 2; i++) {
                int r0 = rowBase + wm * 32 + i * 16 + quad * 4;
                int bidx = r0 >> 11;
                int jj = r0 & 2047;
                ushort* Cz = Cb2 + (long)bidx * DIM * LSP;
#pragma unroll
                for (int j = 0; j < 4; j++) {
                    int c = colBase + wn * 64 + j * 16 + lr;
                    ushort4 o;
                    o.x = f2bf(acc[i][j][0]); o.y = f2bf(acc[i][j][1]);
                    o.z = f2bf(acc[i][j][2]); o.w = f2bf(acc[i][j][3]);
                    *(ushort4*)(Cz + (long)c * LSP + jj) = o;
                }
            }
        }
    } else if (MODE == 2) {
        ushort* Cz = Cb + (long)z * sC;
        float* lz = lsum + (long)z * M;
#pragma unroll
        for (int i = 0; i < 2; i++) {
            int r0 = rowBase + wm * 32 + i * 16 + quad * 4;
#pragma unroll
            for (int reg = 0; reg < 4; reg++) {
                float s = 0.f;
#pragma unroll
                for (int j = 0; j < 4; j++) {
                    int c = colBase + wn * 64 + j * 16 + lr;
                    float e = __expf(acc[i][j][reg] * scale);  // |logit|<=sqrt(768): no max needed
                    s += e;
                    Cz[(long)(r0 + reg) * ldc + c] = f2bf(e);
                }
                for (int m = 1; m < 16; m <<= 1) s += __shfl_xor(s, m, 64);
                if (lr == 0) atomicAdd(&lz[r0 + reg], s);
            }
        }
    } else { // MODE 3 split-K
        float* Cz = (hz ? Cf2 : Cf) + (long)bz * sC;
#pragma unroll
        for (int i = 0; i < 2; i++) {
            int r0 = rowBase + wm * 32 + i * 16 + quad * 4;
#pragma unroll
            for (int j = 0; j < 4; j++) {
                int c = colBase + wn * 64 + j * 16 + lr;
#pragma unroll
                for (int reg = 0; reg < 4; reg++)
                    Cz[(long)(r0 + reg) * ldc + c] = acc[i][j][reg];
            }
        }
    }
}

// ---------------------------------------------------------------------------
// In-place LayerNorm over DIM=768 bf16 values. One wave per row, 12 contiguous
// elems/lane, vectorized ushort4/float4 loads (G13).
// ---------------------------------------------------------------------------
__global__ __launch_bounds__(256) void ln_inplace(
    ushort* __restrict__ X, const float* __restrict__ gamma,
    const float* __restrict__ beta)
{
    int wid = threadIdx.x >> 6, lane = threadIdx.x & 63;
    int row = blockIdx.x * 4 + wid;
    ushort* xp = X + (long)row * DIM + lane * 12;
    ushort4 a0 = *(const ushort4*)xp;
    ushort4 a1 = *(const ushort4*)(xp + 4);
    ushort4 a2 = *(const ushort4*)(xp + 8);
    float v[12];
    v[0] = bf2f(a0.x); v[1] = bf2f(a0.y); v[2]  = bf2f(a0.z); v[3]  = bf2f(a0.w);
    v[4] = bf2f(a1.x); v[5] = bf2f(a1.y); v[6]  = bf2f(a1.z); v[7]  = bf2f(a1.w);
    v[8] = bf2f(a2.x); v[9] = bf2f(a2.y); v[10] = bf2f(a2.z); v[11] = bf2f(a2.w);
    float s = 0.f;
#pragma unroll
    for (int c = 0; c < 12; c++) s += v[c];
    for (int m = 1; m < 64; m <<= 1) s += __shfl_xor(s, m, 64);
    float mean = s * (1.0f / 768.0f);
    float q = 0.f;
#pragma unroll
    for (int c = 0; c < 12; c++) { float d = v[c] - mean; q += d * d; }
    for (int m = 1; m < 64; m <<= 1) q += __shfl_xor(q, m, 64);
    float rstd = rsqrtf(q * (1.0f / 768.0f) + LN_EPS);
    const float* gp = gamma + lane * 12;
    const float* bp = beta + lane * 12;
    float4 g0 = *(const float4*)gp, g1 = *(const float4*)(gp + 4), g2 = *(const float4*)(gp + 8);
    float4 b0 = *(const float4*)bp, b1 = *(const float4*)(bp + 4), b2 = *(const float4*)(bp + 8);
    float gg[12] = {g0.x,g0.y,g0.z,g0.w,g1.x,g1.y,g1.z,g1.w,g2.x,g2.y,g2.z,g2.w};
    float bb[12] = {b0.x,b0.y,b0.z,b0.w,b1.x,b1.y,b1.z,b1.w,b2.x,b2.y,b2.z,b2.w};
    ushort o[12];
#pragma unroll
    for (int c = 0; c < 12; c++)
        o[c] = f2bf((v[c] - mean) * rstd * gg[c] + bb[c]);
    ushort4 w0 = {o[0],o[1],o[2],o[3]}, w1 = {o[4],o[5],o[6],o[7]}, w2 = {o[8],o[9],o[10],o[11]};
    *(ushort4*)xp = w0; *(ushort4*)(xp + 4) = w1; *(ushort4*)(xp + 8) = w2;
}

// ---------------------------------------------------------------------------
// out[row] = softmax_over_d( (O0[row]+O1[row]) / l[row] ). One wave per row,
// 12 contiguous elems/lane, float4 loads/stores.
// ---------------------------------------------------------------------------
__global__ __launch_bounds__(256) void final_softmax(
    const float* __restrict__ O0, const float* __restrict__ O1,
    const float* __restrict__ l, float* __restrict__ out)
{
    int wid = threadIdx.x >> 6, lane = threadIdx.x & 63;
    int row = blockIdx.x * 4 + wid;
    long base = (long)row * DIM + lane * 12;
    float inv = 1.0f / l[row];
    float4 p0 = *(const float4*)(O0 + base);
    float4 p1 = *(const float4*)(O0 + base + 4);
    float4 p2 = *(const float4*)(O0 + base + 8);
    float4 q0 = *(const float4*)(O1 + base);
    float4 q1 = *(const float4*)(O1 + base + 4);
    float4 q2 = *(const float4*)(O1 + base + 8);
    float v[12] = {p0.x+q0.x, p0.y+q0.y, p0.z+q0.z, p0.w+q0.w,
                   p1.x+q1.x, p1.y+q1.y, p1.z+q1.z, p1.w+q1.w,
                   p2.x+q2.x, p2.y+q2.y, p2.z+q2.z, p2.w+q2.w};
    float mx = -1e30f;
#pragma unroll
    for (int c = 0; c < 12; c++) { v[c] *= inv; mx = fmaxf(mx, v[c]); }
    for (int m = 1; m < 64; m <<= 1) mx = fmaxf(mx, __shfl_xor(mx, m, 64));
    float s = 0.f;
#pragma unroll
    for (int c = 0; c < 12; c++) { v[c] = __expf(v[c] - mx); s += v[c]; }
    for (int m = 1; m < 64; m <<= 1) s += __shfl_xor(s, m, 64);
    float invs = 1.0f / s;
    float4 w0 = {v[0]*invs, v[1]*invs, v[2]*invs, v[3]*invs};
    float4 w1 = {v[4]*invs, v[5]*invs, v[6]*invs, v[7]*invs};
    float4 w2 = {v[8]*invs, v[9]*invs, v[10]*invs, v[11]*invs};
    float* op = out + base;
    *(float4*)op = w0; *(float4*)(op + 4) = w1; *(float4*)(op + 8) = w2;
}

// ---------------------------------------------------------------------------
extern "C" void kernel_launch(void* const* d_in, const int* in_sizes, int n_in,
                              void* d_out, int out_size, void* d_ws, size_t ws_size,
                              hipStream_t stream)
{
    const float* Q  = (const float*)d_in[0];
    const float* K_ = (const float*)d_in[1];
    const float* V  = (const float*)d_in[2];
    const float* Wq = (const float*)d_in[3];
    const float* Wk = (const float*)d_in[4];
    const float* Wv = (const float*)d_in[5];
    const float* g  = (const float*)d_in[6];
    const float* b  = (const float*)d_in[7];
    float* out = (float*)d_out;

    char* ws = (char*)d_ws;
    // Workspace layout (bytes). Total ~104.3 MB.
    // P aliases X (lifetime-disjoint); O1 aliases qb+kb (dead after QK).
    ushort* Xq  = (ushort*)(ws + 0);            // 12,582,912 each (Xq,Xk,Xv contig)
    ushort* Wqb = (ushort*)(ws + 37748736);     // 1,179,648 each (contig)
    ushort* qb  = (ushort*)(ws + 41287680);     // 12,582,912 each (qb,kb contig)
    ushort* kb  = (ushort*)(ws + 53870592);
    ushort* vT  = (ushort*)(ws + 66453504);     // 12,582,912
    float*  O0  = (float*)(ws + 79036416);      // 25,165,824
    float*  l   = (float*)(ws + 104202240);     // 32,768
    ushort* P   = (ushort*)(ws + 0);            // 33,554,432 (alias X)
    float*  O1  = (float*)(ws + 41287680);      // 25,165,824 (alias qb+kb)

    (void)in_sizes; (void)n_in; (void)out_size; (void)ws_size;

    hipMemsetAsync(l, 0, NROWS * sizeof(float), stream);

    // 1) gather sparsified rows -> bf16 (z=0..2) + weights -> bf16 (z=3)
    pack4<<<dim3(6144, 1, 4), 256, 0, stream>>>(Q, K_, V, Wq, Wk, Wv, Xq, Wqb);

    // 2) projections: z in {q,k,v}; v stores transposed (vT). 1152 blocks.
    gemm_bt<0, 12><<<dim3(DIM / 128, NROWS / 128, 3), 512, 0, stream>>>(
        Xq, Wqb, qb, vT, nullptr, nullptr, nullptr,
        NROWS, DIM, DIM, DIM,
        (long)NROWS * DIM, (long)DIM * DIM, (long)NROWS * DIM, DIM, 0.f);

    // 3) LayerNorm q and k in place (qb,kb contiguous: 16384 rows)
    ln_inplace<<<4096, 256, 0, stream>>>(qb, g, b);

    // 4) P = exp(scale * q k^T), row-sums into l  (1024 blocks)
    gemm_bt<2, 12><<<dim3(LSP / 128, LSP / 128, BATCH), 512, 0, stream>>>(
        qb, kb, P, nullptr, nullptr, nullptr, l,
        LSP, LSP, DIM, DIM,
        (long)LSP * DIM, (long)LSP * DIM, (long)LSP * LSP, LSP, ATT_SCALE);

    // 5) O = P @ v, split-K x2 (z = batch*2 + half), B operand = vT (768 blocks)
    gemm_bt<3, 16><<<dim3(DIM / 128, LSP / 128, BATCH * 2), 512, 0, stream>>>(
        P, vT, nullptr, nullptr, O0, O1, nullptr,
        LSP, DIM, LSP, LSP,
        (long)LSP * LSP, (long)DIM * LSP, (long)LSP * DIM, DIM, 0.f);

    // 6) out = softmax_d((O0+O1) / l)
    final_softmax<<<2048, 256, 0, stream>>>(O0, O1, l, out);
}